// Round 3
// baseline (296.501 us; speedup 1.0000x reference)
//
#include <hip/hip_runtime.h>
#include <math.h>

constexpr int B_   = 8;
constexpr int C_   = 64;
constexpr int H_   = 256;
constexpr int W_   = 256;
constexpr int CR_  = 128;
constexpr int HIN_ = 128;
constexpr int WIN_ = 128;

typedef float f4v __attribute__((ext_vector_type(4)));  // native vec for nt builtins

// align_corners=True 2x upsample: pos = j * (HIN-1)/(H-1) = j * 127/255
__device__ __forceinline__ float kScale() { return 127.0f / 255.0f; }

// ---------------------------------------------------------------------------
// Stage 1: scores[b, cr] = mean over (H, W) of the bilinearly-upsampled
// readout channel = sum_i sum_l cw[i]*cw[l]*r[i][l]  (separable + linear).
// One block per (b, cr); 256 threads; fully-coalesced float4 column loads.
// ---------------------------------------------------------------------------
__global__ __launch_bounds__(256) void scores_kernel(
    const float* __restrict__ readout, float* __restrict__ scores)
{
    __shared__ float cw[HIN_];
    __shared__ float red[256];
    const int t  = threadIdx.x;
    const int bc = blockIdx.x;        // b*CR + cr

    if (t < HIN_) {
        float acc = 0.0f;
        const float s = kScale();
        for (int j = 0; j < H_; ++j) {
            float pos = j * s;
            int i0 = (int)pos;                 // pos >= 0: trunc == floor
            if (i0 > HIN_ - 2) i0 = HIN_ - 2;
            float w = pos - (float)i0;
            if (i0 == t)     acc += (1.0f - w);
            if (i0 + 1 == t) acc += w;
        }
        cw[t] = acc * (1.0f / 256.0f);
    }
    __syncthreads();

    const int c4 = t & 31;            // float4 column group
    const int rg = t >> 5;            // 0..7 -> 16 rows each
    const f4v* base = (const f4v*)(readout + (size_t)bc * HIN_ * WIN_);

    f4v a4 = (f4v){0.f, 0.f, 0.f, 0.f};
    const int i0r = rg * 16;
#pragma unroll 4
    for (int i = i0r; i < i0r + 16; ++i) {
        const float cwi = cw[i];
        f4v v = base[i * (WIN_ / 4) + c4];
        a4 += cwi * v;
    }
    red[t] = a4.x * cw[4 * c4 + 0] + a4.y * cw[4 * c4 + 1] +
             a4.z * cw[4 * c4 + 2] + a4.w * cw[4 * c4 + 3];
    __syncthreads();
    for (int off = 128; off > 0; off >>= 1) {
        if (t < off) red[t] += red[t + off];
        __syncthreads();
    }
    if (t == 0) scores[bc] = red[0];
}

// ---------------------------------------------------------------------------
// Stage 2: top-C indices per batch, descending, stable (lowest index wins
// ties) — matches jax.lax.top_k. One block per batch, CR threads.
// ---------------------------------------------------------------------------
__global__ __launch_bounds__(CR_) void topk_kernel(
    const float* __restrict__ scores, int* __restrict__ idx)
{
    __shared__ float s[CR_];
    const int t = threadIdx.x;
    const int b = blockIdx.x;
    s[t] = scores[b * CR_ + t];
    __syncthreads();
    const float mine = s[t];
    int rank = 0;
    for (int o = 0; o < CR_; ++o) {
        float so = s[o];
        rank += (so > mine) || (so == mine && o < t);
    }
    if (rank < C_) idx[b * C_ + rank] = t;
}

// ---------------------------------------------------------------------------
// Stage 3: fused upsample-on-the-fly + sigmoid-gated blend.
// Block = 256 threads covering 4 rows x 64 float4 lanes of one (b, c).
// x / out are streamed (touched once) -> non-temporal, keep L2 for readout
// slabs which have ~8x reuse.
// ---------------------------------------------------------------------------
__global__ __launch_bounds__(256) void fuse_kernel(
    const float* __restrict__ x, const float* __restrict__ readout,
    const float* __restrict__ weight, const float* __restrict__ bias,
    const int* __restrict__ idx, float* __restrict__ out)
{
    const int gid = blockIdx.x;
    const int bc  = gid / (H_ / 4);        // b*C + c
    const int h4  = gid % (H_ / 4);
    const int tid = threadIdx.x;
    const int row_in_blk = tid >> 6;       // 0..3
    const int lane       = tid & 63;       // float4 index along W
    const int h = h4 * 4 + row_in_blk;
    const int b = bc / C_;
    const int c = bc % C_;

    const int rc    = idx[b * C_ + c];
    const float w0  = weight[c * 2 + 0];
    const float w1  = weight[c * 2 + 1];
    const float bsv = bias[c];

    const float s = kScale();
    float hpos = h * s;
    int i0 = (int)hpos;
    if (i0 > HIN_ - 2) i0 = HIN_ - 2;
    const float wy = hpos - (float)i0;

    const float* r0 = readout + (((size_t)b * CR_ + rc) * HIN_ + i0) * WIN_;
    const float* r1 = r0 + WIN_;

    const f4v* xin = (const f4v*)(x   + (((size_t)bc) * H_ + h) * W_);
    f4v*       oo  = (f4v*)      (out + (((size_t)bc) * H_ + h) * W_);

    const f4v xv = __builtin_nontemporal_load(&xin[lane]);
    const float xf[4] = {xv.x, xv.y, xv.z, xv.w};
    float rv[4];
    const int wbase = lane * 4;
#pragma unroll
    for (int k = 0; k < 4; ++k) {
        float wpos = (wbase + k) * s;
        int j0 = (int)wpos;
        if (j0 > WIN_ - 2) j0 = WIN_ - 2;
        float wx = wpos - (float)j0;
        float top = r0[j0] + wx * (r0[j0 + 1] - r0[j0]);
        float bot = r1[j0] + wx * (r1[j0 + 1] - r1[j0]);
        rv[k] = top + wy * (bot - top);
    }

    f4v ov;
#pragma unroll
    for (int k = 0; k < 4; ++k) {
        float z = xf[k] * w0 + rv[k] * w1 + bsv;
        float g = 1.0f / (1.0f + __expf(-z));
        ov[k] = xf[k] + g * (rv[k] - xf[k]);
    }
    __builtin_nontemporal_store(ov, &oo[lane]);
}

// ---------------------------------------------------------------------------
extern "C" void kernel_launch(void* const* d_in, const int* in_sizes, int n_in,
                              void* d_out, int out_size, void* d_ws, size_t ws_size,
                              hipStream_t stream)
{
    const float* x       = (const float*)d_in[0];   // [B, C, H, W]
    const float* readout = (const float*)d_in[1];   // [B, CR, HIN, WIN]
    const float* weight  = (const float*)d_in[2];   // [C, 2, 1, 1]
    const float* bias    = (const float*)d_in[3];   // [C]
    float* out = (float*)d_out;                     // [B, C, H, W]

    float* scores = (float*)d_ws;                                   // B*CR floats
    int*   idx    = (int*)((char*)d_ws + B_ * CR_ * sizeof(float)); // B*C ints

    scores_kernel<<<B_ * CR_, 256, 0, stream>>>(readout, scores);
    topk_kernel<<<B_, CR_, 0, stream>>>(scores, idx);
    fuse_kernel<<<B_ * C_ * (H_ / 4), 256, 0, stream>>>(x, readout, weight, bias, idx, out);
}

// Round 4
// 282.751 us; speedup vs baseline: 1.0486x; 1.0486x over previous
//
#include <hip/hip_runtime.h>
#include <math.h>

constexpr int B_   = 8;
constexpr int C_   = 64;
constexpr int H_   = 256;
constexpr int W_   = 256;
constexpr int CR_  = 128;
constexpr int HIN_ = 128;
constexpr int WIN_ = 128;

typedef float f4v __attribute__((ext_vector_type(4)));              // 16B-aligned
typedef float f4u __attribute__((ext_vector_type(4), aligned(4)));  // unaligned vec4

// align_corners=True 2x upsample: pos = j * (HIN-1)/(H-1) = j * 127/255
__device__ __forceinline__ float kScale() { return 127.0f / 255.0f; }

// ---------------------------------------------------------------------------
// Stage 1: scores[b, cr] = mean over (H, W) of the bilinearly-upsampled
// readout channel = sum_i sum_l cw[i]*cw[l]*r[i][l]  (separable + linear).
// One block per (b, cr); 256 threads; fully-coalesced float4 column loads.
// cw loop restricted to the <=7 output rows that can touch input row t.
// ---------------------------------------------------------------------------
__global__ __launch_bounds__(256) void scores_kernel(
    const float* __restrict__ readout, float* __restrict__ scores)
{
    __shared__ float cw[HIN_];
    __shared__ float red[256];
    const int t  = threadIdx.x;
    const int bc = blockIdx.x;        // b*CR + cr

    if (t < HIN_) {
        float acc = 0.0f;
        const float s = kScale();
        int jlo = 2 * t - 3; if (jlo < 0) jlo = 0;
        int jhi = 2 * t + 3; if (jhi > H_ - 1) jhi = H_ - 1;
        for (int j = jlo; j <= jhi; ++j) {
            float pos = j * s;
            int i0 = (int)pos;                 // pos >= 0: trunc == floor
            if (i0 > HIN_ - 2) i0 = HIN_ - 2;
            float w = pos - (float)i0;
            if (i0 == t)     acc += (1.0f - w);
            if (i0 + 1 == t) acc += w;
        }
        cw[t] = acc * (1.0f / 256.0f);
    }
    __syncthreads();

    const int c4 = t & 31;            // float4 column group
    const int rg = t >> 5;            // 0..7 -> 16 rows each
    const f4v* base = (const f4v*)(readout + (size_t)bc * HIN_ * WIN_);

    f4v a4 = (f4v){0.f, 0.f, 0.f, 0.f};
    const int i0r = rg * 16;
#pragma unroll 4
    for (int i = i0r; i < i0r + 16; ++i) {
        const float cwi = cw[i];
        f4v v = base[i * (WIN_ / 4) + c4];
        a4 += cwi * v;
    }
    red[t] = a4.x * cw[4 * c4 + 0] + a4.y * cw[4 * c4 + 1] +
             a4.z * cw[4 * c4 + 2] + a4.w * cw[4 * c4 + 3];
    __syncthreads();
    for (int off = 128; off > 0; off >>= 1) {
        if (t < off) red[t] += red[t + off];
        __syncthreads();
    }
    if (t == 0) scores[bc] = red[0];
}

// ---------------------------------------------------------------------------
// Stage 2: top-C indices per batch, descending, stable (lowest index wins
// ties) — matches jax.lax.top_k. One block per batch, CR threads.
// ---------------------------------------------------------------------------
__global__ __launch_bounds__(CR_) void topk_kernel(
    const float* __restrict__ scores, int* __restrict__ idx)
{
    __shared__ float s[CR_];
    const int t = threadIdx.x;
    const int b = blockIdx.x;
    s[t] = scores[b * CR_ + t];
    __syncthreads();
    const float mine = s[t];
    int rank = 0;
    for (int o = 0; o < CR_; ++o) {
        float so = s[o];
        rank += (so > mine) || (so == mine && o < t);
    }
    if (rank < C_) idx[b * C_ + rank] = t;
}

// neighbor selects from a 4-float window; d in {0,1,2}
__device__ __forceinline__ float sel_a(f4u w, int d) {
    return d == 0 ? w[0] : (d == 1 ? w[1] : w[2]);
}
__device__ __forceinline__ float sel_b(f4u w, int d) {
    return d == 0 ? w[1] : (d == 1 ? w[2] : w[3]);
}

// ---------------------------------------------------------------------------
// Stage 3: fused upsample-on-the-fly + sigmoid-gated blend.
// Block = 256 threads covering 4 rows x 64 float4 lanes of one (b, c).
// Per lane, the 4 output pixels' horizontal neighbors span <= 4 consecutive
// readout floats -> ONE unaligned vec4 load per row (2 total) replaces 16
// scalar loads. x / out streamed non-temporally (touched once); readout kept
// cacheable (L2/L3 reuse after scores pass).
// ---------------------------------------------------------------------------
__global__ __launch_bounds__(256) void fuse_kernel(
    const float* __restrict__ x, const float* __restrict__ readout,
    const float* __restrict__ weight, const float* __restrict__ bias,
    const int* __restrict__ idx, float* __restrict__ out)
{
    const int gid = blockIdx.x;
    const int bc  = gid >> 6;              // b*C + c   (H/4 == 64)
    const int h4  = gid & 63;
    const int tid = threadIdx.x;
    const int row_in_blk = tid >> 6;       // 0..3
    const int lane       = tid & 63;       // float4 index along W
    const int h = h4 * 4 + row_in_blk;
    const int b = bc >> 6;                 // C == 64
    const int c = bc & 63;

    const int rc    = idx[b * C_ + c];
    const float w0  = weight[c * 2 + 0];
    const float w1  = weight[c * 2 + 1];
    const float bsv = bias[c];

    const float s = kScale();
    float hpos = h * s;
    int i0 = (int)hpos;
    if (i0 > HIN_ - 2) i0 = HIN_ - 2;
    const float wy = hpos - (float)i0;

    const float* r0 = readout + (((size_t)b * CR_ + rc) * HIN_ + i0) * WIN_;
    const float* r1 = r0 + WIN_;

    const f4v* xin = (const f4v*)(x   + (((size_t)bc) * H_ + h) * W_);
    f4v*       oo  = (f4v*)      (out + (((size_t)bc) * H_ + h) * W_);

    // horizontal neighbor indices/weights for this lane's 4 outputs
    int   j0c[4];
    float wx[4];
    const int wbase = lane * 4;
#pragma unroll
    for (int k = 0; k < 4; ++k) {
        float wpos = (wbase + k) * s;
        int j0 = (int)wpos;
        if (j0 > WIN_ - 2) j0 = WIN_ - 2;
        wx[k]  = wpos - (float)j0;
        j0c[k] = j0;
    }
    int j00 = j0c[0];
    if (j00 > WIN_ - 4) j00 = WIN_ - 4;    // keep [j00..j00+3] in-bounds

    const f4v xv  = __builtin_nontemporal_load(&xin[lane]);
    const f4u w0v = *(const f4u*)(r0 + j00);
    const f4u w1v = *(const f4u*)(r1 + j00);

    const float xf[4] = {xv.x, xv.y, xv.z, xv.w};
    f4v ov;
#pragma unroll
    for (int k = 0; k < 4; ++k) {
        const int d = j0c[k] - j00;        // 0..2
        float ta = sel_a(w0v, d), tb = sel_b(w0v, d);
        float ba = sel_a(w1v, d), bb = sel_b(w1v, d);
        float top = ta + wx[k] * (tb - ta);
        float bot = ba + wx[k] * (bb - ba);
        float rv  = top + wy * (bot - top);

        float z = xf[k] * w0 + rv * w1 + bsv;
        float g = 1.0f / (1.0f + __expf(-z));
        ov[k] = xf[k] + g * (rv - xf[k]);
    }
    __builtin_nontemporal_store(ov, &oo[lane]);
}

// ---------------------------------------------------------------------------
extern "C" void kernel_launch(void* const* d_in, const int* in_sizes, int n_in,
                              void* d_out, int out_size, void* d_ws, size_t ws_size,
                              hipStream_t stream)
{
    const float* x       = (const float*)d_in[0];   // [B, C, H, W]
    const float* readout = (const float*)d_in[1];   // [B, CR, HIN, WIN]
    const float* weight  = (const float*)d_in[2];   // [C, 2, 1, 1]
    const float* bias    = (const float*)d_in[3];   // [C]
    float* out = (float*)d_out;                     // [B, C, H, W]

    float* scores = (float*)d_ws;                                   // B*CR floats
    int*   idx    = (int*)((char*)d_ws + B_ * CR_ * sizeof(float)); // B*C ints

    scores_kernel<<<B_ * CR_, 256, 0, stream>>>(readout, scores);
    topk_kernel<<<B_, CR_, 0, stream>>>(scores, idx);
    fuse_kernel<<<B_ * C_ * (H_ / 4), 256, 0, stream>>>(x, readout, weight, bias, idx, out);
}